// Round 6
// baseline (89.588 us; speedup 1.0000x reference)
//
#include <hip/hip_runtime.h>
#include <hip/hip_bf16.h>

#define BATCH 8192
#define NF 512
#define NL 1024
#define ATOMS 513

typedef float float4v __attribute__((ext_vector_type(4)));
typedef short short8 __attribute__((ext_vector_type(8)));

// fp32 -> bf16 bits, round-to-nearest-even
__device__ __forceinline__ unsigned short f2bf(float f) {
    union { float f; unsigned int u; } cv; cv.f = f;
    unsigned int u = cv.u;
    u += 0x7fffu + ((u >> 16) & 1u);
    return (unsigned short)(u >> 16);
}

// async 16B/lane global->LDS: lane i lands at ldsbase + i*16 (wave-uniform base)
__device__ __forceinline__ void load_lds16(const unsigned short* g, unsigned short* ldsbase) {
    __builtin_amdgcn_global_load_lds(
        (const __attribute__((address_space(1))) unsigned int*)g,
        (__attribute__((address_space(3))) unsigned int*)ldsbase,
        16, 0, 0);
}

// s_waitcnt with only vmcnt constrained (exp=7, lgkm=15 i.e. unconstrained).
// gfx9 bitfield: vm[3:0], exp[6:4], lgkm[11:8], vm_hi[15:14]
#define WAIT_VMCNT_8() __builtin_amdgcn_s_waitcnt(0x0F78)
#define WAIT_VMCNT_0() __builtin_amdgcn_s_waitcnt(0x0F70)

// ---------------- Kernel 0: X fp32 -> bf16 ----------------
__global__ void convert_kernel(const float* __restrict__ X,
                               unsigned short* __restrict__ Xb) {
    size_t i = ((size_t)blockIdx.x * 256 + threadIdx.x) * 8;
    float4v x0 = *reinterpret_cast<const float4v*>(X + i);
    float4v x1 = *reinterpret_cast<const float4v*>(X + i + 4);
    short8 a;
    a[0] = (short)f2bf(x0[0]); a[1] = (short)f2bf(x0[1]);
    a[2] = (short)f2bf(x0[2]); a[3] = (short)f2bf(x0[3]);
    a[4] = (short)f2bf(x1[0]); a[5] = (short)f2bf(x1[1]);
    a[6] = (short)f2bf(x1[2]); a[7] = (short)f2bf(x1[3]);
    *reinterpret_cast<short8*>(Xb + i) = a;
}

// ---------------- Kernel 1: per-leaf softmax over 513 atoms ----------------
__global__ void softmax_kernel(const float* __restrict__ logits,
                               unsigned short* __restrict__ Wb,
                               float* __restrict__ bias) {
    int l = blockIdx.x;
    int t = threadIdx.x;
    int wave = t >> 6, lane = t & 63;
    const float* row = logits + (size_t)l * ATOMS;
    float v0 = row[t];
    float v1 = row[t + 256];
    float v2 = (t == 0) ? row[512] : -1e30f;

    __shared__ float red[8];
    float m = fmaxf(fmaxf(v0, v1), v2);
#pragma unroll
    for (int o = 32; o > 0; o >>= 1) m = fmaxf(m, __shfl_xor(m, o, 64));
    if (lane == 0) red[wave] = m;
    __syncthreads();
    float mx = fmaxf(fmaxf(red[0], red[1]), fmaxf(red[2], red[3]));

    float e0 = __expf(v0 - mx);
    float e1 = __expf(v1 - mx);
    float e2 = (t == 0) ? __expf(v2 - mx) : 0.f;
    float s = e0 + e1 + e2;
#pragma unroll
    for (int o = 32; o > 0; o >>= 1) s += __shfl_xor(s, o, 64);
    if (lane == 0) red[4 + wave] = s;
    __syncthreads();
    float inv = 1.f / (red[4] + red[5] + red[6] + red[7]);

    unsigned short* wrow = Wb + (size_t)l * NF;
    if (t == 0) {
        bias[l] = e0 * inv;            // atom 0 (constant 1)
        wrow[511] = f2bf(e2 * inv);    // atom 512 -> k=511
    } else {
        wrow[t - 1] = f2bf(e0 * inv);  // atoms 1..255 -> k=0..254
    }
    wrow[t + 255] = f2bf(e1 * inv);    // atoms 256..511 -> k=255..510
}

// ---------------- Kernel 2: barrier-free per-wave-pipelined MFMA GEMM ----------------
// Grid: 512 blocks = 64 row-tiles x 8 leaf-tiles, nb-fastest.
// 4 waves in 2x2; wave computes 64x64 via 4x4 mfma_f32_16x16x32_bf16 tiles.
// Each wave stages ITS OWN A(64x32) and B(64x32) sub-tiles into private LDS
// double-buffers -> no cross-wave LDS deps -> NO __syncthreads in the K-loop.
// Per-wave pipeline: stage(kt+1), s_waitcnt vmcnt(8) (kt's 8 stages done,
// kt+1's 8 still in flight), ds_read, MFMA. Buffer reuse distance 2 is safe:
// stage(kt+1) overwrites buf(kt-1) whose ds_reads completed before kt-1's
// MFMAs issued (in-order issue within a wave).
__global__ __launch_bounds__(256, 2)
void gemm_lse_kernel(const unsigned short* __restrict__ Xb,
                     const unsigned short* __restrict__ Wb,
                     const float* __restrict__ bias,
                     float* __restrict__ partial) {
    // per wave: 2 buffers x (A 2048 shorts + B 2048 shorts) = 16 KB
    __shared__ unsigned short lds[4][2][4096];
    __shared__ float sums[2][128];

    int tid  = threadIdx.x;
    int wave = tid >> 6;
    int lane = tid & 63;
    int quad = lane >> 4;
    int l16  = lane & 15;
    int wr = wave >> 1;      // wave row (0..1) -> 64 batch rows
    int wc = wave & 1;       // wave col (0..1) -> 64 leaves

    int mb = blockIdx.x >> 3;     // nb-fastest
    int nb = blockIdx.x & 7;
    int R0 = mb * 128;
    int N0 = nb * 128;

    unsigned short* myL = &lds[wave][0][0];

    // staging source: lane i covers row i/4 (of 16-row chunk), bytes (i%4)*16
    const unsigned short* gA = Xb + (size_t)(R0 + wr * 64 + (lane >> 2)) * NF + (lane & 3) * 8;
    const unsigned short* gB = Wb + (size_t)(N0 + wc * 64 + (lane >> 2)) * NF + (lane & 3) * 8;

    float4v acc[4][4];
#pragma unroll
    for (int mt = 0; mt < 4; ++mt)
#pragma unroll
        for (int nt = 0; nt < 4; ++nt)
            acc[mt][nt] = (float4v){0.f, 0.f, 0.f, 0.f};

    // prologue: stage kt=0 into buffer 0 (8 loads)
#pragma unroll
    for (int j = 0; j < 4; ++j) {
        load_lds16(gA + j * 16 * NF, myL + j * 512);
        load_lds16(gB + j * 16 * NF, myL + 2048 + j * 512);
    }

    for (int kt = 0; kt < 16; ++kt) {
        int cur = kt & 1;
        if (kt < 15) {
            unsigned short* dst = myL + (cur ^ 1) * 4096;
            const unsigned short* a = gA + (kt + 1) * 32;
            const unsigned short* b = gB + (kt + 1) * 32;
#pragma unroll
            for (int j = 0; j < 4; ++j) {
                load_lds16(a + j * 16 * NF, dst + j * 512);
                load_lds16(b + j * 16 * NF, dst + 2048 + j * 512);
            }
            WAIT_VMCNT_8();   // kt's stages done; kt+1's 8 remain in flight
        } else {
            WAIT_VMCNT_0();
        }

        const unsigned short* base = myL + cur * 4096;
        short8 af[4], bfr[4];
#pragma unroll
        for (int mt = 0; mt < 4; ++mt)
            af[mt] = *reinterpret_cast<const short8*>(base + (mt * 16 + l16) * 32 + quad * 8);
#pragma unroll
        for (int nt = 0; nt < 4; ++nt)
            bfr[nt] = *reinterpret_cast<const short8*>(base + 2048 + (nt * 16 + l16) * 32 + quad * 8);

#pragma unroll
        for (int mt = 0; mt < 4; ++mt)
#pragma unroll
            for (int nt = 0; nt < 4; ++nt)
                acc[mt][nt] = __builtin_amdgcn_mfma_f32_16x16x32_bf16(
                    af[mt], bfr[nt], acc[mt][nt], 0, 0, 0);
    }

    // Epilogue: per C-row partial sum of exp(c + bias) over this wave's 64 leaves
    float bl[4];
#pragma unroll
    for (int nt = 0; nt < 4; ++nt)
        bl[nt] = bias[N0 + wc * 64 + nt * 16 + l16];

    float ps[4][4];
#pragma unroll
    for (int mt = 0; mt < 4; ++mt)
#pragma unroll
        for (int r = 0; r < 4; ++r) ps[mt][r] = 0.f;

#pragma unroll
    for (int nt = 0; nt < 4; ++nt)
#pragma unroll
        for (int mt = 0; mt < 4; ++mt)
#pragma unroll
            for (int r = 0; r < 4; ++r)
                ps[mt][r] += __expf(acc[mt][nt][r] + bl[nt]);

    // reduce across the 16 columns (xor masks < 16 stay within quad group)
#pragma unroll
    for (int m = 1; m < 16; m <<= 1)
#pragma unroll
        for (int mt = 0; mt < 4; ++mt)
#pragma unroll
            for (int r = 0; r < 4; ++r)
                ps[mt][r] += __shfl_xor(ps[mt][r], m, 64);

    if (l16 == 0) {
#pragma unroll
        for (int mt = 0; mt < 4; ++mt)
#pragma unroll
            for (int r = 0; r < 4; ++r)
                sums[wc][wr * 64 + mt * 16 + quad * 4 + r] = ps[mt][r];
    }
    __syncthreads();
    if (tid < 128)
        partial[(size_t)nb * BATCH + R0 + tid] = sums[0][tid] + sums[1][tid];
}

// ---------------- Kernel 3: combine 8 leaf-panel partials, take log ----------------
__global__ void combine_kernel(const float* __restrict__ partial,
                               float* __restrict__ out) {
    int i = blockIdx.x * 256 + threadIdx.x;
    float s = 0.f;
#pragma unroll
    for (int c = 0; c < 8; ++c) s += partial[(size_t)c * BATCH + i];
    out[i] = logf(s);
}

extern "C" void kernel_launch(void* const* d_in, const int* in_sizes, int n_in,
                              void* d_out, int out_size, void* d_ws, size_t ws_size,
                              hipStream_t stream) {
    const float* X      = (const float*)d_in[0];   // (8192, 512) fp32
    const float* logits = (const float*)d_in[1];   // (1024, 513) fp32
    float* out = (float*)d_out;                    // (8192,) fp32

    char* ws = (char*)d_ws;
    unsigned short* Xb   = (unsigned short*)ws;                                   // 8 MB
    unsigned short* Wb   = (unsigned short*)(ws + (size_t)BATCH * NF * 2);        // 1 MB
    float* bias = (float*)(ws + (size_t)BATCH * NF * 2 + (size_t)NL * NF * 2);    // 4 KB
    float* part = (float*)((char*)bias + NL * sizeof(float));                     // 256 KB

    convert_kernel<<<(BATCH * NF) / (256 * 8), 256, 0, stream>>>(X, Xb);
    softmax_kernel<<<NL, 256, 0, stream>>>(logits, Wb, bias);
    gemm_lse_kernel<<<(BATCH / 128) * (NL / 128), 256, 0, stream>>>(Xb, Wb, bias, part);
    combine_kernel<<<BATCH / 256, 256, 0, stream>>>(part, out);
}

// Round 7
// 87.198 us; speedup vs baseline: 1.0274x; 1.0274x over previous
//
#include <hip/hip_runtime.h>
#include <hip/hip_bf16.h>

#define BATCH 8192
#define NF 512
#define NL 1024
#define ATOMS 513

typedef float float4v __attribute__((ext_vector_type(4)));
typedef int int4v __attribute__((ext_vector_type(4)));

// fp32 -> fp8 e4m3 (OCP) byte via HW pack instruction
__device__ __forceinline__ unsigned char f2fp8(float x) {
    return (unsigned char)(__builtin_amdgcn_cvt_pk_fp8_f32(x, x, 0, false) & 0xff);
}

// async 16B/lane global->LDS: lane i lands at ldsbase + i*16 (wave-uniform base)
__device__ __forceinline__ void load_lds16(const void* g, void* ldsbase) {
    __builtin_amdgcn_global_load_lds(
        (const __attribute__((address_space(1))) unsigned int*)g,
        (__attribute__((address_space(3))) unsigned int*)ldsbase,
        16, 0, 0);
}

// ---------------- Kernel 0: X fp32 -> fp8 e4m3 (16 elems/thread) ----------------
__global__ void convert_kernel(const float* __restrict__ X,
                               unsigned char* __restrict__ X8) {
    size_t i = ((size_t)blockIdx.x * 256 + threadIdx.x) * 16;
    const float4v* p = reinterpret_cast<const float4v*>(X + i);
    float4v a = p[0], b = p[1], c = p[2], d = p[3];
    int4v o;
    int w;
    w = __builtin_amdgcn_cvt_pk_fp8_f32(a[0], a[1], 0, false);
    w = __builtin_amdgcn_cvt_pk_fp8_f32(a[2], a[3], w, true);
    o[0] = w;
    w = __builtin_amdgcn_cvt_pk_fp8_f32(b[0], b[1], 0, false);
    w = __builtin_amdgcn_cvt_pk_fp8_f32(b[2], b[3], w, true);
    o[1] = w;
    w = __builtin_amdgcn_cvt_pk_fp8_f32(c[0], c[1], 0, false);
    w = __builtin_amdgcn_cvt_pk_fp8_f32(c[2], c[3], w, true);
    o[2] = w;
    w = __builtin_amdgcn_cvt_pk_fp8_f32(d[0], d[1], 0, false);
    w = __builtin_amdgcn_cvt_pk_fp8_f32(d[2], d[3], w, true);
    o[3] = w;
    *reinterpret_cast<int4v*>(X8 + i) = o;
}

// ---------------- Kernel 1: per-leaf softmax; W' = 512*w in fp8, bias fp32 ----------------
__global__ void softmax_kernel(const float* __restrict__ logits,
                               unsigned char* __restrict__ W8,
                               float* __restrict__ bias) {
    int l = blockIdx.x;
    int t = threadIdx.x;
    int wave = t >> 6, lane = t & 63;
    const float* row = logits + (size_t)l * ATOMS;
    float v0 = row[t];
    float v1 = row[t + 256];
    float v2 = (t == 0) ? row[512] : -1e30f;

    __shared__ float red[8];
    float m = fmaxf(fmaxf(v0, v1), v2);
#pragma unroll
    for (int o = 32; o > 0; o >>= 1) m = fmaxf(m, __shfl_xor(m, o, 64));
    if (lane == 0) red[wave] = m;
    __syncthreads();
    float mx = fmaxf(fmaxf(red[0], red[1]), fmaxf(red[2], red[3]));

    float e0 = __expf(v0 - mx);
    float e1 = __expf(v1 - mx);
    float e2 = (t == 0) ? __expf(v2 - mx) : 0.f;
    float s = e0 + e1 + e2;
#pragma unroll
    for (int o = 32; o > 0; o >>= 1) s += __shfl_xor(s, o, 64);
    if (lane == 0) red[4 + wave] = s;
    __syncthreads();
    float inv = 1.f / (red[4] + red[5] + red[6] + red[7]);
    float inv512 = inv * 512.f;   // scaled so fp8 values sit near 1.0 (not subnormal)

    unsigned char* wrow = W8 + (size_t)l * NF;
    if (t == 0) {
        bias[l] = e0 * inv;                // atom 0 (constant 1), exact fp32
        wrow[511] = f2fp8(e2 * inv512);    // atom 512 -> k=511
    } else {
        wrow[t - 1] = f2fp8(e0 * inv512);  // atoms 1..255 -> k=0..254
    }
    wrow[t + 255] = f2fp8(e1 * inv512);    // atoms 256..511 -> k=255..510
}

// ---------------- Kernel 2: fp8 MFMA GEMM (BK=64, dbuf, swizzled LDS) ----------------
// Grid: 512 blocks = 64 row-tiles x 8 leaf-tiles, nb-fastest (per-XCD: one 64KB
// B panel L2-resident + 4MB X8 ~ L2-sized). 4 waves 2x2, wave = 64x64 via 4x4
// tiles of mfma_f32_16x16x32_fp8_fp8 (2 MFMA per k-tile pair, K=64/kt, 8 kt).
// LDS rows are 64B; 16B chunk g of row r is stored at chunk (g+r)&3 (XOR-ish
// swizzle) so b64 fragment reads hit the 4-phase floor instead of 8-way.
__global__ __launch_bounds__(256, 2)
void gemm_lse_kernel(const unsigned char* __restrict__ X8,
                     const unsigned char* __restrict__ W8,
                     const float* __restrict__ bias,
                     float* __restrict__ partial) {
    __shared__ unsigned char As[2][128 * 64];
    __shared__ unsigned char Bs[2][128 * 64];
    __shared__ float sums[2][128];

    int tid  = threadIdx.x;
    int wave = tid >> 6;
    int lane = tid & 63;
    int quad = lane >> 4;
    int l16  = lane & 15;
    int wr = wave >> 1;      // wave row (0..1) -> 64 batch rows
    int wc = wave & 1;       // wave col (0..1) -> 64 leaves

    int mb = blockIdx.x >> 3;
    int nb = blockIdx.x & 7;
    int R0 = mb * 128;
    int N0 = nb * 128;

    // staging: wave stages rows [wave*32, wave*32+32); lane -> row +lane/4.
    // source chunk swizzle: LDS chunk c=(lane&3) of row r=(lane>>2) holds
    // global chunk g=(c - r)&3  (so global chunk g lives at LDS chunk (g+r)&3)
    int srow  = wave * 32 + (lane >> 2);
    int schunk = ((lane & 3) - (lane >> 2)) & 3;
    const unsigned char* gA = X8 + (size_t)(R0 + srow) * NF + schunk * 16;
    const unsigned char* gB = W8 + (size_t)(N0 + srow) * NF + schunk * 16;

    float4v acc[4][4];
#pragma unroll
    for (int mt = 0; mt < 4; ++mt)
#pragma unroll
        for (int nt = 0; nt < 4; ++nt)
            acc[mt][nt] = (float4v){0.f, 0.f, 0.f, 0.f};

    // prologue: stage kt=0 into buffer 0 (2 A + 2 B instrs per wave)
    load_lds16(gA,           &As[0][(wave * 32) * 64]);
    load_lds16(gA + 16 * NF, &As[0][(wave * 32 + 16) * 64]);
    load_lds16(gB,           &Bs[0][(wave * 32) * 64]);
    load_lds16(gB + 16 * NF, &Bs[0][(wave * 32 + 16) * 64]);
    __syncthreads();

    for (int kt = 0; kt < 8; ++kt) {
        int cur = kt & 1;
        if (kt < 7) {
            int nxt = cur ^ 1;
            const unsigned char* a = gA + (kt + 1) * 64;
            const unsigned char* b = gB + (kt + 1) * 64;
            load_lds16(a,           &As[nxt][(wave * 32) * 64]);
            load_lds16(a + 16 * NF, &As[nxt][(wave * 32 + 16) * 64]);
            load_lds16(b,           &Bs[nxt][(wave * 32) * 64]);
            load_lds16(b + 16 * NF, &Bs[nxt][(wave * 32 + 16) * 64]);
        }

        // fragment reads: want bytes [s*32+quad*8, +8) of row r ->
        // global chunk g = s*2 + (quad>>1), LDS chunk (g+r)&3, inner (quad&1)*8
        long af[4][2], bfr[4][2];
#pragma unroll
        for (int mt = 0; mt < 4; ++mt) {
            int r = wr * 64 + mt * 16 + l16;
#pragma unroll
            for (int s = 0; s < 2; ++s) {
                int g = s * 2 + (quad >> 1);
                int off = r * 64 + (((g + r) & 3) * 16) + (quad & 1) * 8;
                af[mt][s] = *reinterpret_cast<const long*>(&As[cur][off]);
            }
        }
#pragma unroll
        for (int nt = 0; nt < 4; ++nt) {
            int r = wc * 64 + nt * 16 + l16;
#pragma unroll
            for (int s = 0; s < 2; ++s) {
                int g = s * 2 + (quad >> 1);
                int off = r * 64 + (((g + r) & 3) * 16) + (quad & 1) * 8;
                bfr[nt][s] = *reinterpret_cast<const long*>(&Bs[cur][off]);
            }
        }

#pragma unroll
        for (int mt = 0; mt < 4; ++mt)
#pragma unroll
            for (int nt = 0; nt < 4; ++nt) {
                acc[mt][nt] = __builtin_amdgcn_mfma_f32_16x16x32_fp8_fp8(
                    af[mt][0], bfr[nt][0], acc[mt][nt], 0, 0, 0);
                acc[mt][nt] = __builtin_amdgcn_mfma_f32_16x16x32_fp8_fp8(
                    af[mt][1], bfr[nt][1], acc[mt][nt], 0, 0, 0);
            }
        __syncthreads();   // all waves done reading buf cur; prefetch drained
    }

    // Epilogue: c = acc/512 + bias; partial sum of exp over this wave's 64 leaves
    float bl[4];
#pragma unroll
    for (int nt = 0; nt < 4; ++nt)
        bl[nt] = bias[N0 + wc * 64 + nt * 16 + l16];

    const float INV512 = 0.001953125f;
    float ps[4][4];
#pragma unroll
    for (int mt = 0; mt < 4; ++mt)
#pragma unroll
        for (int r = 0; r < 4; ++r) ps[mt][r] = 0.f;

#pragma unroll
    for (int nt = 0; nt < 4; ++nt)
#pragma unroll
        for (int mt = 0; mt < 4; ++mt)
#pragma unroll
            for (int r = 0; r < 4; ++r)
                ps[mt][r] += __expf(fmaf(acc[mt][nt][r], INV512, bl[nt]));

    // reduce across the 16 columns (xor masks < 16 stay within quad group)
#pragma unroll
    for (int m = 1; m < 16; m <<= 1)
#pragma unroll
        for (int mt = 0; mt < 4; ++mt)
#pragma unroll
            for (int r = 0; r < 4; ++r)
                ps[mt][r] += __shfl_xor(ps[mt][r], m, 64);

    if (l16 == 0) {
#pragma unroll
        for (int mt = 0; mt < 4; ++mt)
#pragma unroll
            for (int r = 0; r < 4; ++r)
                sums[wc][wr * 64 + mt * 16 + quad * 4 + r] = ps[mt][r];
    }
    __syncthreads();
    if (tid < 128)
        partial[(size_t)nb * BATCH + R0 + tid] = sums[0][tid] + sums[1][tid];
}

// ---------------- Kernel 3: combine 8 leaf-panel partials, take log ----------------
__global__ void combine_kernel(const float* __restrict__ partial,
                               float* __restrict__ out) {
    int i = blockIdx.x * 256 + threadIdx.x;
    float s = 0.f;
#pragma unroll
    for (int c = 0; c < 8; ++c) s += partial[(size_t)c * BATCH + i];
    out[i] = logf(s);
}

extern "C" void kernel_launch(void* const* d_in, const int* in_sizes, int n_in,
                              void* d_out, int out_size, void* d_ws, size_t ws_size,
                              hipStream_t stream) {
    const float* X      = (const float*)d_in[0];   // (8192, 512) fp32
    const float* logits = (const float*)d_in[1];   // (1024, 513) fp32
    float* out = (float*)d_out;                    // (8192,) fp32

    char* ws = (char*)d_ws;
    unsigned char* X8 = (unsigned char*)ws;                                  // 4 MB
    unsigned char* W8 = (unsigned char*)(ws + (size_t)BATCH * NF);           // 0.5 MB
    float* bias = (float*)(ws + (size_t)BATCH * NF + (size_t)NL * NF);       // 4 KB
    float* part = (float*)((char*)bias + NL * sizeof(float));                // 256 KB

    convert_kernel<<<(BATCH * NF) / (256 * 16), 256, 0, stream>>>(X, X8);
    softmax_kernel<<<NL, 256, 0, stream>>>(logits, W8, bias);
    gemm_lse_kernel<<<(BATCH / 128) * (NL / 128), 256, 0, stream>>>(X8, W8, bias, part);
    combine_kernel<<<BATCH / 256, 256, 0, stream>>>(part, out);
}

// Round 8
// 85.599 us; speedup vs baseline: 1.0466x; 1.0187x over previous
//
#include <hip/hip_runtime.h>
#include <hip/hip_bf16.h>

#define BATCH 8192
#define NF 512
#define NL 1024
#define ATOMS 513

typedef float float4v __attribute__((ext_vector_type(4)));
typedef int int4v __attribute__((ext_vector_type(4)));

// fp32 -> fp8 e4m3 (OCP) byte via HW pack instruction
__device__ __forceinline__ unsigned char f2fp8(float x) {
    return (unsigned char)(__builtin_amdgcn_cvt_pk_fp8_f32(x, x, 0, false) & 0xff);
}

// async 16B/lane global->LDS: lane i lands at ldsbase + i*16 (wave-uniform base)
__device__ __forceinline__ void load_lds16(const void* g, void* ldsbase) {
    __builtin_amdgcn_global_load_lds(
        (const __attribute__((address_space(1))) unsigned int*)g,
        (__attribute__((address_space(3))) unsigned int*)ldsbase,
        16, 0, 0);
}

// ---------------- Kernel 0: X fp32 -> fp8 e4m3 (16 elems/thread) ----------------
__global__ void convert_kernel(const float* __restrict__ X,
                               unsigned char* __restrict__ X8) {
    size_t i = ((size_t)blockIdx.x * 256 + threadIdx.x) * 16;
    const float4v* p = reinterpret_cast<const float4v*>(X + i);
    float4v a = p[0], b = p[1], c = p[2], d = p[3];
    int4v o;
    int w;
    w = __builtin_amdgcn_cvt_pk_fp8_f32(a[0], a[1], 0, false);
    w = __builtin_amdgcn_cvt_pk_fp8_f32(a[2], a[3], w, true);
    o[0] = w;
    w = __builtin_amdgcn_cvt_pk_fp8_f32(b[0], b[1], 0, false);
    w = __builtin_amdgcn_cvt_pk_fp8_f32(b[2], b[3], w, true);
    o[1] = w;
    w = __builtin_amdgcn_cvt_pk_fp8_f32(c[0], c[1], 0, false);
    w = __builtin_amdgcn_cvt_pk_fp8_f32(c[2], c[3], w, true);
    o[2] = w;
    w = __builtin_amdgcn_cvt_pk_fp8_f32(d[0], d[1], 0, false);
    w = __builtin_amdgcn_cvt_pk_fp8_f32(d[2], d[3], w, true);
    o[3] = w;
    *reinterpret_cast<int4v*>(X8 + i) = o;
}

// ---------------- Kernel 1: per-leaf softmax; W' = 512*w in fp8, bias fp32 ----------------
__global__ void softmax_kernel(const float* __restrict__ logits,
                               unsigned char* __restrict__ W8,
                               float* __restrict__ bias) {
    int l = blockIdx.x;
    int t = threadIdx.x;
    int wave = t >> 6, lane = t & 63;
    const float* row = logits + (size_t)l * ATOMS;
    float v0 = row[t];
    float v1 = row[t + 256];
    float v2 = (t == 0) ? row[512] : -1e30f;

    __shared__ float red[8];
    float m = fmaxf(fmaxf(v0, v1), v2);
#pragma unroll
    for (int o = 32; o > 0; o >>= 1) m = fmaxf(m, __shfl_xor(m, o, 64));
    if (lane == 0) red[wave] = m;
    __syncthreads();
    float mx = fmaxf(fmaxf(red[0], red[1]), fmaxf(red[2], red[3]));

    float e0 = __expf(v0 - mx);
    float e1 = __expf(v1 - mx);
    float e2 = (t == 0) ? __expf(v2 - mx) : 0.f;
    float s = e0 + e1 + e2;
#pragma unroll
    for (int o = 32; o > 0; o >>= 1) s += __shfl_xor(s, o, 64);
    if (lane == 0) red[4 + wave] = s;
    __syncthreads();
    float inv = 1.f / (red[4] + red[5] + red[6] + red[7]);
    float inv512 = inv * 512.f;   // keep fp8 values near 1.0 (out of subnormal range)

    unsigned char* wrow = W8 + (size_t)l * NF;
    if (t == 0) {
        bias[l] = e0 * inv;                // atom 0 (constant 1), exact fp32
        wrow[511] = f2fp8(e2 * inv512);    // atom 512 -> k=511
    } else {
        wrow[t - 1] = f2fp8(e0 * inv512);  // atoms 1..255 -> k=0..254
    }
    wrow[t + 255] = f2fp8(e1 * inv512);    // atoms 256..511 -> k=255..510
}

// ---------------- Kernel 2: fp8 MFMA GEMM, 64x128 tile, 4 blocks/CU ----------------
// Grid: 1024 blocks = 128 row-tiles x 8 leaf-tiles, nb-fastest (XCD x always
// sees nb=x -> its 64KB B panel is L2-resident; 4 independent blocks/CU for
// latency overlap across barrier drains).
// Block: 64 rows x 128 leaves, 4 waves 2x2: wave = 32 rows x 64 leaves
// (2x4 tiles of mfma_f32_16x16x32_fp8_fp8, 2 MFMA per tile per kt, BK=64, 8 kt).
// LDS: As[2][64*64] + Bs[2][128*64] = 24KB, XOR chunk swizzle
// (global 16B-chunk g of local row r lives at LDS chunk g^(r&3)) -> b64 reads
// at the 4-phase byte floor. All 12 fragment offsets are kt-invariant ->
// precomputed before the (fully unrolled) K-loop.
__global__ __launch_bounds__(256, 4)
void gemm_lse_kernel(const unsigned char* __restrict__ X8,
                     const unsigned char* __restrict__ W8,
                     const float* __restrict__ bias,
                     float* __restrict__ partial) {
    __shared__ unsigned char As[2][64 * 64];
    __shared__ unsigned char Bs[2][128 * 64];
    __shared__ float sums[2][64];

    int tid  = threadIdx.x;
    int wave = tid >> 6;
    int lane = tid & 63;
    int quad = lane >> 4;
    int l16  = lane & 15;
    int wr = wave >> 1;      // wave row (0..1) -> 32 batch rows
    int wc = wave & 1;       // wave col (0..1) -> 64 leaves

    int mb = blockIdx.x >> 3;
    int nb = blockIdx.x & 7;
    int R0 = mb * 64;
    int N0 = nb * 128;

    // ---- staging addresses (source chunk XOR-swizzled to match readers) ----
    int sr = lane >> 2;                       // 0..15 row within 16-row chunk
    int gch = (lane & 3) ^ (sr & 3);          // global chunk this lane fetches
    // A: wave stages local rows [wave*16, wave*16+16)
    const unsigned char* gA = X8 + (size_t)(R0 + wave * 16 + sr) * NF + gch * 16;
    // B: wave stages local rows [wave*32, wave*32+32) via two instructions
    const unsigned char* gB = W8 + (size_t)(N0 + wave * 32 + sr) * NF + gch * 16;

    // ---- fragment LDS byte offsets (kt-invariant) ----
    int aoff[2][2], boff[4][2];
#pragma unroll
    for (int mt = 0; mt < 2; ++mt) {
        int r = wr * 32 + mt * 16 + l16;
#pragma unroll
        for (int s = 0; s < 2; ++s) {
            int g = s * 2 + (quad >> 1);
            aoff[mt][s] = r * 64 + ((g ^ (r & 3)) * 16) + (quad & 1) * 8;
        }
    }
#pragma unroll
    for (int nt = 0; nt < 4; ++nt) {
        int r = wc * 64 + nt * 16 + l16;
#pragma unroll
        for (int s = 0; s < 2; ++s) {
            int g = s * 2 + (quad >> 1);
            boff[nt][s] = r * 64 + ((g ^ (r & 3)) * 16) + (quad & 1) * 8;
        }
    }

    float4v acc[2][4];
#pragma unroll
    for (int mt = 0; mt < 2; ++mt)
#pragma unroll
        for (int nt = 0; nt < 4; ++nt)
            acc[mt][nt] = (float4v){0.f, 0.f, 0.f, 0.f};

    // prologue: stage kt=0 into buffer 0 (1 A + 2 B instrs per wave)
    load_lds16(gA,           &As[0][wave * 16 * 64]);
    load_lds16(gB,           &Bs[0][wave * 32 * 64]);
    load_lds16(gB + 16 * NF, &Bs[0][(wave * 32 + 16) * 64]);
    __syncthreads();

#pragma unroll
    for (int kt = 0; kt < 8; ++kt) {
        const int cur = kt & 1;
        if (kt < 7) {
            const int nxt = cur ^ 1;
            const unsigned char* a = gA + (kt + 1) * 64;
            const unsigned char* b = gB + (kt + 1) * 64;
            load_lds16(a,           &As[nxt][wave * 16 * 64]);
            load_lds16(b,           &Bs[nxt][wave * 32 * 64]);
            load_lds16(b + 16 * NF, &Bs[nxt][(wave * 32 + 16) * 64]);
        }

        long af[2][2], bfr[4][2];
#pragma unroll
        for (int mt = 0; mt < 2; ++mt)
#pragma unroll
            for (int s = 0; s < 2; ++s)
                af[mt][s] = *reinterpret_cast<const long*>(&As[cur][aoff[mt][s]]);
#pragma unroll
        for (int nt = 0; nt < 4; ++nt)
#pragma unroll
            for (int s = 0; s < 2; ++s)
                bfr[nt][s] = *reinterpret_cast<const long*>(&Bs[cur][boff[nt][s]]);

#pragma unroll
        for (int mt = 0; mt < 2; ++mt)
#pragma unroll
            for (int nt = 0; nt < 4; ++nt) {
                acc[mt][nt] = __builtin_amdgcn_mfma_f32_16x16x32_fp8_fp8(
                    af[mt][0], bfr[nt][0], acc[mt][nt], 0, 0, 0);
                acc[mt][nt] = __builtin_amdgcn_mfma_f32_16x16x32_fp8_fp8(
                    af[mt][1], bfr[nt][1], acc[mt][nt], 0, 0, 0);
            }
        __syncthreads();   // all waves done with buf cur; prefetch drained
    }

    // Epilogue: c = acc/512 + bias; partial sum of exp over this wave's 64 leaves
    float bl[4];
#pragma unroll
    for (int nt = 0; nt < 4; ++nt)
        bl[nt] = bias[N0 + wc * 64 + nt * 16 + l16];

    const float INV512 = 0.001953125f;
    float ps[2][4];
#pragma unroll
    for (int mt = 0; mt < 2; ++mt)
#pragma unroll
        for (int r = 0; r < 4; ++r) ps[mt][r] = 0.f;

#pragma unroll
    for (int nt = 0; nt < 4; ++nt)
#pragma unroll
        for (int mt = 0; mt < 2; ++mt)
#pragma unroll
            for (int r = 0; r < 4; ++r)
                ps[mt][r] += __expf(fmaf(acc[mt][nt][r], INV512, bl[nt]));

    // reduce across the 16 columns (xor masks < 16 stay within quad group)
#pragma unroll
    for (int m = 1; m < 16; m <<= 1)
#pragma unroll
        for (int mt = 0; mt < 2; ++mt)
#pragma unroll
            for (int r = 0; r < 4; ++r)
                ps[mt][r] += __shfl_xor(ps[mt][r], m, 64);

    if (l16 == 0) {
#pragma unroll
        for (int mt = 0; mt < 2; ++mt)
#pragma unroll
            for (int r = 0; r < 4; ++r)
                sums[wc][wr * 32 + mt * 16 + quad * 4 + r] = ps[mt][r];
    }
    __syncthreads();
    if (tid < 64)
        partial[(size_t)nb * BATCH + R0 + tid] = sums[0][tid] + sums[1][tid];
}

// ---------------- Kernel 3: combine 8 leaf-panel partials, take log ----------------
__global__ void combine_kernel(const float* __restrict__ partial,
                               float* __restrict__ out) {
    int i = blockIdx.x * 256 + threadIdx.x;
    float s = 0.f;
#pragma unroll
    for (int c = 0; c < 8; ++c) s += partial[(size_t)c * BATCH + i];
    out[i] = logf(s);
}

extern "C" void kernel_launch(void* const* d_in, const int* in_sizes, int n_in,
                              void* d_out, int out_size, void* d_ws, size_t ws_size,
                              hipStream_t stream) {
    const float* X      = (const float*)d_in[0];   // (8192, 512) fp32
    const float* logits = (const float*)d_in[1];   // (1024, 513) fp32
    float* out = (float*)d_out;                    // (8192,) fp32

    char* ws = (char*)d_ws;
    unsigned char* X8 = (unsigned char*)ws;                                  // 4 MB
    unsigned char* W8 = (unsigned char*)(ws + (size_t)BATCH * NF);           // 0.5 MB
    float* bias = (float*)(ws + (size_t)BATCH * NF + (size_t)NL * NF);       // 4 KB
    float* part = (float*)((char*)bias + NL * sizeof(float));                // 256 KB

    convert_kernel<<<(BATCH * NF) / (256 * 16), 256, 0, stream>>>(X, X8);
    softmax_kernel<<<NL, 256, 0, stream>>>(logits, W8, bias);
    gemm_lse_kernel<<<(BATCH / 64) * (NL / 128), 256, 0, stream>>>(X8, W8, bias, part);
    combine_kernel<<<BATCH / 256, 256, 0, stream>>>(part, out);
}

// Round 10
// 79.330 us; speedup vs baseline: 1.1293x; 1.0790x over previous
//
#include <hip/hip_runtime.h>
#include <hip/hip_bf16.h>

#define BATCH 8192
#define NF 512
#define NL 1024
#define ATOMS 513

typedef float float4v __attribute__((ext_vector_type(4)));
typedef int int4v __attribute__((ext_vector_type(4)));
typedef long long2v __attribute__((ext_vector_type(2)));

// fp32 -> fp8 e4m3 (OCP) byte via HW pack instruction
__device__ __forceinline__ unsigned char f2fp8(float x) {
    return (unsigned char)(__builtin_amdgcn_cvt_pk_fp8_f32(x, x, 0, false) & 0xff);
}

// Fragment-packed layouts (kpair-interleaved):
//   Xp[rt (512)][kp (8)][lane (64)][16B]   rt = row/16
//   Wp[lt  (64)][kp (8)][lane (64)][16B]   lt = leaf/16
// lane = quad*16 + l16. The 16 bytes are the lane's A/B operand for MFMA
// k-slices ks=2kp (bytes 0..8) and ks=2kp+1 (bytes 8..16):
//   bytes[half*8 + b] = M[rt*16 + l16][ (2kp+half)*32 + quad*8 + b ]

// ---------------- Kernel 0: X fp32 -> fp8, packed into Xp fragment order ----------------
// One block per rowtile (16 rows x 512 k). Coalesced reads -> LDS fp8 tile ->
// coalesced fragment-order writes.
__global__ void convert_kernel(const float* __restrict__ X,
                               unsigned char* __restrict__ Xp) {
    __shared__ unsigned char tile[16 * 512];   // 8 KB, [row][k]
    int t  = threadIdx.x;
    int rt = blockIdx.x;
    const float* base = X + (size_t)rt * 16 * 512;

    // phase 1: contiguous float4 reads (i*1024 + t*4), fp8-pack, LDS store.
    // int index of packed word for floats [i*1024 + t*4, +4) is i*256 + t.
#pragma unroll
    for (int i = 0; i < 8; ++i) {
        float4v v = *reinterpret_cast<const float4v*>(base + (size_t)i * 1024 + t * 4);
        int w = __builtin_amdgcn_cvt_pk_fp8_f32(v[0], v[1], 0, false);
        w = __builtin_amdgcn_cvt_pk_fp8_f32(v[2], v[3], w, true);
        reinterpret_cast<int*>(tile)[i * 256 + t] = w;
    }
    __syncthreads();

    // phase 2: thread t -> kp = t>>5, lanes 2j, 2j+1 (j = t&31); 32B contiguous store
    int kp = t >> 5, j = t & 31;
#pragma unroll
    for (int e = 0; e < 2; ++e) {
        int ln = 2 * j + e;
        int l16 = ln & 15, quad = ln >> 4;
        const int* s0 = reinterpret_cast<const int*>(tile + l16 * 512 + (2 * kp) * 32 + quad * 8);
        const int* s1 = reinterpret_cast<const int*>(tile + l16 * 512 + (2 * kp + 1) * 32 + quad * 8);
        int4v o = (int4v){s0[0], s0[1], s1[0], s1[1]};
        *reinterpret_cast<int4v*>(Xp + (((size_t)rt * 8 + kp) * 64 + ln) * 16) = o;
    }
}

// byte offset of weight (leaf l, k) inside Wp
__device__ __forceinline__ size_t wp_off(int l, int k) {
    int lt = l >> 4, l16 = l & 15;
    int ks = k >> 5, kp = ks >> 1, half = ks & 1;
    int quad = (k >> 3) & 3, byt = k & 7;
    return ((size_t)((lt * 8 + kp) * 64) + quad * 16 + l16) * 16 + half * 8 + byt;
}

// ---------------- Kernel 1: per-leaf softmax; W' = 512*w packed into Wp ----------------
__global__ void softmax_kernel(const float* __restrict__ logits,
                               unsigned char* __restrict__ Wp,
                               float* __restrict__ bias) {
    int l = blockIdx.x;
    int t = threadIdx.x;
    int wave = t >> 6, lane = t & 63;
    const float* row = logits + (size_t)l * ATOMS;
    float v0 = row[t];
    float v1 = row[t + 256];
    float v2 = (t == 0) ? row[512] : -1e30f;

    __shared__ float red[8];
    float m = fmaxf(fmaxf(v0, v1), v2);
#pragma unroll
    for (int o = 32; o > 0; o >>= 1) m = fmaxf(m, __shfl_xor(m, o, 64));
    if (lane == 0) red[wave] = m;
    __syncthreads();
    float mx = fmaxf(fmaxf(red[0], red[1]), fmaxf(red[2], red[3]));

    float e0 = __expf(v0 - mx);
    float e1 = __expf(v1 - mx);
    float e2 = (t == 0) ? __expf(v2 - mx) : 0.f;
    float s = e0 + e1 + e2;
#pragma unroll
    for (int o = 32; o > 0; o >>= 1) s += __shfl_xor(s, o, 64);
    if (lane == 0) red[4 + wave] = s;
    __syncthreads();
    float inv = 1.f / (red[4] + red[5] + red[6] + red[7]);
    float inv512 = inv * 512.f;   // keep fp8 values near 1.0 (out of subnormal range)

    if (t == 0) {
        bias[l] = e0 * inv;                      // atom 0 (constant 1), fp32
        Wp[wp_off(l, 511)] = f2fp8(e2 * inv512); // atom 512 -> k=511
    } else {
        Wp[wp_off(l, t - 1)] = f2fp8(e0 * inv512);   // atoms 1..255 -> k=0..254
    }
    Wp[wp_off(l, t + 255)] = f2fp8(e1 * inv512);     // atoms 256..511 -> k=255..510
}

// ---------------- Kernel 2: LDS-free, barrier-free fp8 MFMA GEMM + exp-sum ----------------
// Grid: 512 blocks = 64 row-superblocks x 8 leaf-groups (lg fastest -> XCD's
// 64KB B panel is L2/L1-resident; all 4 waves of a block share it via L1).
// Wave: 32 rows (mt=2 rowtiles) x 128 leaves (nt=8 leaftiles).
// K-loop: per kpair, 10 coalesced dwordx4 frag loads + 32 MFMAs; NO LDS, NO
// barriers -> compiler emits per-dependency vmcnt(N); loads pipeline freely.
__global__ __launch_bounds__(256, 2)
void gemm_lse_kernel(const unsigned char* __restrict__ Xp,
                     const unsigned char* __restrict__ Wp,
                     const float* __restrict__ bias,
                     float* __restrict__ partial) {
    __shared__ float sums[128];

    int tid  = threadIdx.x;
    int wave = tid >> 6;
    int lane = tid & 63;
    int quad = lane >> 4;
    int l16  = lane & 15;

    int lg  = blockIdx.x & 7;    // leaf group: leaves [lg*128, +128)
    int rsb = blockIdx.x >> 3;   // row superblock: rows [rsb*128, +128)

    // wave's A rowtiles: rt = rsb*8 + wave*2 + mt ; B leaftiles: lt = lg*8 + nt
    const unsigned char* pa = Xp + (((size_t)(rsb * 8 + wave * 2) * 8) * 64 + lane) * 16;
    const unsigned char* pb = Wp + (((size_t)(lg * 8) * 8) * 64 + lane) * 16;

    float4v acc[2][8];
#pragma unroll
    for (int mt = 0; mt < 2; ++mt)
#pragma unroll
        for (int nt = 0; nt < 8; ++nt)
            acc[mt][nt] = (float4v){0.f, 0.f, 0.f, 0.f};

#pragma unroll
    for (int kp = 0; kp < 8; ++kp) {
        long2v af[2], bf[8];
#pragma unroll
        for (int mt = 0; mt < 2; ++mt)
            af[mt] = *reinterpret_cast<const long2v*>(pa + (size_t)mt * 8192 + kp * 1024);
#pragma unroll
        for (int nt = 0; nt < 8; ++nt)
            bf[nt] = *reinterpret_cast<const long2v*>(pb + (size_t)nt * 8192 + kp * 1024);

#pragma unroll
        for (int mt = 0; mt < 2; ++mt)
#pragma unroll
            for (int nt = 0; nt < 8; ++nt) {
                acc[mt][nt] = __builtin_amdgcn_mfma_f32_16x16x32_fp8_fp8(
                    af[mt][0], bf[nt][0], acc[mt][nt], 0, 0, 0);
                acc[mt][nt] = __builtin_amdgcn_mfma_f32_16x16x32_fp8_fp8(
                    af[mt][1], bf[nt][1], acc[mt][nt], 0, 0, 0);
            }
    }

    // Epilogue: c = acc/512 + bias; sum exp over this wave's 128 leaves
    float bl[8];
#pragma unroll
    for (int nt = 0; nt < 8; ++nt)
        bl[nt] = bias[lg * 128 + nt * 16 + l16];

    const float INV512 = 0.001953125f;
    float ps[2][4];
#pragma unroll
    for (int mt = 0; mt < 2; ++mt)
#pragma unroll
        for (int r = 0; r < 4; ++r) ps[mt][r] = 0.f;

#pragma unroll
    for (int nt = 0; nt < 8; ++nt)
#pragma unroll
        for (int mt = 0; mt < 2; ++mt)
#pragma unroll
            for (int r = 0; r < 4; ++r)
                ps[mt][r] += __expf(fmaf(acc[mt][nt][r], INV512, bl[nt]));

    // reduce across the 16 columns (xor masks < 16 stay within the quad group)
#pragma unroll
    for (int m = 1; m < 16; m <<= 1)
#pragma unroll
        for (int mt = 0; mt < 2; ++mt)
#pragma unroll
            for (int r = 0; r < 4; ++r)
                ps[mt][r] += __shfl_xor(ps[mt][r], m, 64);

    if (l16 == 0) {
#pragma unroll
        for (int mt = 0; mt < 2; ++mt)
#pragma unroll
            for (int r = 0; r < 4; ++r)
                sums[wave * 32 + mt * 16 + quad * 4 + r] = ps[mt][r];
    }
    __syncthreads();
    if (tid < 128)
        partial[(size_t)lg * BATCH + rsb * 128 + tid] = sums[tid];
}

// ---------------- Kernel 3: combine 8 leaf-panel partials, take log ----------------
__global__ void combine_kernel(const float* __restrict__ partial,
                               float* __restrict__ out) {
    int i = blockIdx.x * 256 + threadIdx.x;
    float s = 0.f;
#pragma unroll
    for (int c = 0; c < 8; ++c) s += partial[(size_t)c * BATCH + i];
    out[i] = logf(s);
}

extern "C" void kernel_launch(void* const* d_in, const int* in_sizes, int n_in,
                              void* d_out, int out_size, void* d_ws, size_t ws_size,
                              hipStream_t stream) {
    const float* X      = (const float*)d_in[0];   // (8192, 512) fp32
    const float* logits = (const float*)d_in[1];   // (1024, 513) fp32
    float* out = (float*)d_out;                    // (8192,) fp32

    char* ws = (char*)d_ws;
    unsigned char* Xp = (unsigned char*)ws;                                  // 4 MB
    unsigned char* Wp = (unsigned char*)(ws + (size_t)BATCH * NF);           // 512 KB
    float* bias = (float*)(ws + (size_t)BATCH * NF + (size_t)NL * NF);       // 4 KB
    float* part = (float*)((char*)bias + NL * sizeof(float));                // 256 KB

    convert_kernel<<<BATCH / 16, 256, 0, stream>>>(X, Xp);
    softmax_kernel<<<NL, 256, 0, stream>>>(logits, Wp, bias);
    gemm_lse_kernel<<<(BATCH / 128) * (NL / 128), 256, 0, stream>>>(Xp, Wp, bias, part);
    combine_kernel<<<BATCH / 256, 256, 0, stream>>>(part, out);
}

// Round 11
// 78.621 us; speedup vs baseline: 1.1395x; 1.0090x over previous
//
#include <hip/hip_runtime.h>
#include <hip/hip_bf16.h>

#define BATCH 8192
#define NF 512
#define NL 1024
#define ATOMS 513

typedef float float4v __attribute__((ext_vector_type(4)));
typedef int int4v __attribute__((ext_vector_type(4)));
typedef long long2v __attribute__((ext_vector_type(2)));

// fp32 -> fp8 e4m3 (OCP) byte via HW pack instruction
__device__ __forceinline__ unsigned char f2fp8(float x) {
    return (unsigned char)(__builtin_amdgcn_cvt_pk_fp8_f32(x, x, 0, false) & 0xff);
}

// async 16B/lane global->LDS: lane i lands at ldsbase + i*16 (wave-uniform LDS base,
// per-lane source address)
__device__ __forceinline__ void load_lds16(const void* g, void* ldsbase) {
    __builtin_amdgcn_global_load_lds(
        (const __attribute__((address_space(1))) unsigned int*)g,
        (__attribute__((address_space(3))) unsigned int*)ldsbase,
        16, 0, 0);
}

// Fragment-packed layouts (kpair-interleaved):
//   Xp[rt (512)][kp (8)][lane (64)][16B]   rt = row/16
//   Wp[lt  (64)][kp (8)][lane (64)][16B]   lt = leaf/16
// lane = quad*16 + l16. bytes[half*8 + b] = M[rt*16 + l16][(2kp+half)*32 + quad*8 + b]

#define N_CONVERT_BLOCKS 512   // BATCH/16
#define N_SOFTMAX_BLOCKS 1024

// ---------------- Kernel 1: fused prep (convert-pack + softmax-pack) ----------------
__global__ void prep_kernel(const float* __restrict__ X,
                            const float* __restrict__ logits,
                            unsigned char* __restrict__ Xp,
                            unsigned char* __restrict__ Wp,
                            float* __restrict__ bias) {
    int bi = blockIdx.x;
    int t  = threadIdx.x;

    if (bi < N_CONVERT_BLOCKS) {
        // ---- role A: X fp32 -> fp8 packed into Xp fragment order ----
        __shared__ unsigned char tile[16 * 512];   // 8 KB, [row][k]
        int rt = bi;
        const float* base = X + (size_t)rt * 16 * 512;
#pragma unroll
        for (int i = 0; i < 8; ++i) {
            float4v v = *reinterpret_cast<const float4v*>(base + (size_t)i * 1024 + t * 4);
            int w = __builtin_amdgcn_cvt_pk_fp8_f32(v[0], v[1], 0, false);
            w = __builtin_amdgcn_cvt_pk_fp8_f32(v[2], v[3], w, true);
            reinterpret_cast<int*>(tile)[i * 256 + t] = w;
        }
        __syncthreads();
        int kp = t >> 5, j = t & 31;
#pragma unroll
        for (int e = 0; e < 2; ++e) {
            int ln = 2 * j + e;
            int l16 = ln & 15, quad = ln >> 4;
            const int* s0 = reinterpret_cast<const int*>(tile + l16 * 512 + (2 * kp) * 32 + quad * 8);
            const int* s1 = reinterpret_cast<const int*>(tile + l16 * 512 + (2 * kp + 1) * 32 + quad * 8);
            int4v o = (int4v){s0[0], s0[1], s1[0], s1[1]};
            *reinterpret_cast<int4v*>(Xp + (((size_t)rt * 8 + kp) * 64 + ln) * 16) = o;
        }
        return;
    }

    // ---- role B: per-leaf softmax; W' = 512*w packed into Wp ----
    int l = bi - N_CONVERT_BLOCKS;
    int wave = t >> 6, lane = t & 63;
    const float* row = logits + (size_t)l * ATOMS;
    float v0 = row[t];
    float v1 = row[t + 256];
    float v2 = (t == 0) ? row[512] : -1e30f;

    __shared__ float red[8];
    float m = fmaxf(fmaxf(v0, v1), v2);
#pragma unroll
    for (int o = 32; o > 0; o >>= 1) m = fmaxf(m, __shfl_xor(m, o, 64));
    if (lane == 0) red[wave] = m;
    __syncthreads();
    float mx = fmaxf(fmaxf(red[0], red[1]), fmaxf(red[2], red[3]));

    float e0 = __expf(v0 - mx);
    float e1 = __expf(v1 - mx);
    float e2 = (t == 0) ? __expf(v2 - mx) : 0.f;
    float s = e0 + e1 + e2;
#pragma unroll
    for (int o = 32; o > 0; o >>= 1) s += __shfl_xor(s, o, 64);
    if (lane == 0) red[4 + wave] = s;
    __syncthreads();
    float inv = 1.f / (red[4] + red[5] + red[6] + red[7]);
    float inv512 = inv * 512.f;   // keep fp8 near 1.0 (out of subnormal range)

    // byte offset of weight (leaf l, k) inside Wp
    auto wp_off = [](int l_, int k_) -> size_t {
        int lt = l_ >> 4, l16_ = l_ & 15;
        int ks = k_ >> 5, kp_ = ks >> 1, half = ks & 1;
        int quad_ = (k_ >> 3) & 3, byt = k_ & 7;
        return ((size_t)((lt * 8 + kp_) * 64) + quad_ * 16 + l16_) * 16 + half * 8 + byt;
    };

    if (t == 0) {
        bias[l] = e0 * inv;                      // atom 0 (constant 1), fp32
        Wp[wp_off(l, 511)] = f2fp8(e2 * inv512); // atom 512 -> k=511
    } else {
        Wp[wp_off(l, t - 1)] = f2fp8(e0 * inv512);   // atoms 1..255 -> k=0..254
    }
    Wp[wp_off(l, t + 255)] = f2fp8(e1 * inv512);     // atoms 256..511 -> k=255..510
}

// ---------------- Kernel 2: fp8 MFMA GEMM; B panel in LDS (staged once), A global ----------------
// Grid: 512 blocks = 64 row-superblocks x 8 leaf-groups (lg fastest -> XCD x's
// B panel stays L2-local for the one-time stage). Wave: 32 rows x 128 leaves.
// B panel (64 KB = whole lg's fragments) staged to LDS once via 64
// global_load_lds, ONE barrier, then a barrier-free K-loop:
//   per kp: 2 global dwordx4 A-frag loads + 8 conflict-free ds_read_b128
//   B-frag loads + 32 MFMAs. vmcnt/lgkmcnt are per-dependency (no drains).
__global__ __launch_bounds__(256, 2)
void gemm_lse_kernel(const unsigned char* __restrict__ Xp,
                     const unsigned char* __restrict__ Wp,
                     const float* __restrict__ bias,
                     float* __restrict__ partial) {
    __shared__ unsigned char Bl[64 * 1024];   // whole B panel, fragment order
    __shared__ float sums[128];

    int tid  = threadIdx.x;
    int wave = tid >> 6;
    int lane = tid & 63;
    int quad = lane >> 4;
    int l16  = lane & 15;

    int lg  = blockIdx.x & 7;    // leaf group: leaves [lg*128, +128)
    int rsb = blockIdx.x >> 3;   // row superblock: rows [rsb*128, +128)

    // one-time B panel stage: wave w covers bytes [w*16K, w*16K+16K)
    {
        const unsigned char* gb = Wp + (size_t)lg * 65536 + wave * 16384 + lane * 16;
        unsigned char* lb = Bl + wave * 16384;   // wave-uniform LDS base
#pragma unroll
        for (int j = 0; j < 16; ++j)
            load_lds16(gb + j * 1024, lb + j * 1024);
    }

    // A fragment pointer (per-lane): rowtiles rt = rsb*8 + wave*2 + mt
    const unsigned char* pa = Xp + ((size_t)(rsb * 8 + wave * 2) * 8) * 1024 + lane * 16;

    float4v acc[2][8];
#pragma unroll
    for (int mt = 0; mt < 2; ++mt)
#pragma unroll
        for (int nt = 0; nt < 8; ++nt)
            acc[mt][nt] = (float4v){0.f, 0.f, 0.f, 0.f};

    __syncthreads();   // B panel resident (also drains the global_load_lds)

#pragma unroll
    for (int kp = 0; kp < 8; ++kp) {
        long2v af[2], bf[8];
#pragma unroll
        for (int mt = 0; mt < 2; ++mt)
            af[mt] = *reinterpret_cast<const long2v*>(pa + (size_t)mt * 8192 + kp * 1024);
#pragma unroll
        for (int nt = 0; nt < 8; ++nt)
            bf[nt] = *reinterpret_cast<const long2v*>(Bl + (nt * 8 + kp) * 1024 + lane * 16);

#pragma unroll
        for (int mt = 0; mt < 2; ++mt)
#pragma unroll
            for (int nt = 0; nt < 8; ++nt) {
                acc[mt][nt] = __builtin_amdgcn_mfma_f32_16x16x32_fp8_fp8(
                    af[mt][0], bf[nt][0], acc[mt][nt], 0, 0, 0);
                acc[mt][nt] = __builtin_amdgcn_mfma_f32_16x16x32_fp8_fp8(
                    af[mt][1], bf[nt][1], acc[mt][nt], 0, 0, 0);
            }
    }

    // Epilogue: c = acc/512 + bias; sum exp over this wave's 128 leaves
    float bl[8];
#pragma unroll
    for (int nt = 0; nt < 8; ++nt)
        bl[nt] = bias[lg * 128 + nt * 16 + l16];

    const float INV512 = 0.001953125f;
    float ps[2][4];
#pragma unroll
    for (int mt = 0; mt < 2; ++mt)
#pragma unroll
        for (int r = 0; r < 4; ++r) ps[mt][r] = 0.f;

#pragma unroll
    for (int nt = 0; nt < 8; ++nt)
#pragma unroll
        for (int mt = 0; mt < 2; ++mt)
#pragma unroll
            for (int r = 0; r < 4; ++r)
                ps[mt][r] += __expf(fmaf(acc[mt][nt][r], INV512, bl[nt]));

    // reduce across the 16 columns (xor masks < 16 stay within the quad group)
#pragma unroll
    for (int m = 1; m < 16; m <<= 1)
#pragma unroll
        for (int mt = 0; mt < 2; ++mt)
#pragma unroll
            for (int r = 0; r < 4; ++r)
                ps[mt][r] += __shfl_xor(ps[mt][r], m, 64);

    if (l16 == 0) {
#pragma unroll
        for (int mt = 0; mt < 2; ++mt)
#pragma unroll
            for (int r = 0; r < 4; ++r)
                sums[wave * 32 + mt * 16 + quad * 4 + r] = ps[mt][r];
    }
    __syncthreads();
    if (tid < 128)
        partial[(size_t)lg * BATCH + rsb * 128 + tid] = sums[tid];
}

// ---------------- Kernel 3: combine 8 leaf-panel partials, take log ----------------
__global__ void combine_kernel(const float* __restrict__ partial,
                               float* __restrict__ out) {
    int i = blockIdx.x * 256 + threadIdx.x;
    float s = 0.f;
#pragma unroll
    for (int c = 0; c < 8; ++c) s += partial[(size_t)c * BATCH + i];
    out[i] = logf(s);
}

extern "C" void kernel_launch(void* const* d_in, const int* in_sizes, int n_in,
                              void* d_out, int out_size, void* d_ws, size_t ws_size,
                              hipStream_t stream) {
    const float* X      = (const float*)d_in[0];   // (8192, 512) fp32
    const float* logits = (const float*)d_in[1];   // (1024, 513) fp32
    float* out = (float*)d_out;                    // (8192,) fp32

    char* ws = (char*)d_ws;
    unsigned char* Xp = (unsigned char*)ws;                                  // 4 MB
    unsigned char* Wp = (unsigned char*)(ws + (size_t)BATCH * NF);           // 512 KB
    float* bias = (float*)(ws + (size_t)BATCH * NF + (size_t)NL * NF);       // 4 KB
    float* part = (float*)((char*)bias + NL * sizeof(float));                // 256 KB

    prep_kernel<<<N_CONVERT_BLOCKS + N_SOFTMAX_BLOCKS, 256, 0, stream>>>(X, logits, Xp, Wp, bias);
    gemm_lse_kernel<<<(BATCH / 128) * (NL / 128), 256, 0, stream>>>(Xp, Wp, bias, part);
    combine_kernel<<<BATCH / 256, 256, 0, stream>>>(part, out);
}

// Round 12
// 78.488 us; speedup vs baseline: 1.1414x; 1.0017x over previous
//
#include <hip/hip_runtime.h>
#include <hip/hip_bf16.h>

#define BATCH 8192
#define NF 512
#define NL 1024
#define ATOMS 513

typedef float float4v __attribute__((ext_vector_type(4)));
typedef int int4v __attribute__((ext_vector_type(4)));
typedef long long2v __attribute__((ext_vector_type(2)));

// fp32 -> fp8 e4m3 (OCP) byte via HW pack instruction
__device__ __forceinline__ unsigned char f2fp8(float x) {
    return (unsigned char)(__builtin_amdgcn_cvt_pk_fp8_f32(x, x, 0, false) & 0xff);
}

// async 16B/lane global->LDS: lane i lands at ldsbase + i*16
__device__ __forceinline__ void load_lds16(const void* g, void* ldsbase) {
    __builtin_amdgcn_global_load_lds(
        (const __attribute__((address_space(1))) unsigned int*)g,
        (__attribute__((address_space(3))) unsigned int*)ldsbase,
        16, 0, 0);
}

// Fragment-packed layouts (kpair-interleaved):
//   Xp[rt (512)][kp (8)][lane (64)][16B]   rt = row/16
//   Wp[lt  (64)][kp (8)][lane (64)][16B]   lt = leaf/16
// lane = quad*16 + l16. bytes[half*8 + b] = M[rt*16 + l16][(2kp+half)*32 + quad*8 + b]

#define N_CONVERT_BLOCKS 512   // BATCH/16
#define N_SOFTMAX_BLOCKS 1024
#define N_ZERO_BLOCKS    33    // ceil((8192 + 64)/256)

// ---------------- Kernel 1: fused prep (convert-pack + softmax-pack + zero-init) ----------------
__global__ void prep_kernel(const float* __restrict__ X,
                            const float* __restrict__ logits,
                            unsigned char* __restrict__ Xp,
                            unsigned char* __restrict__ Wp,
                            float* __restrict__ bias,
                            float* __restrict__ sumexp,
                            int* __restrict__ cnt) {
    int bi = blockIdx.x;
    int t  = threadIdx.x;

    if (bi < N_CONVERT_BLOCKS) {
        // ---- role A: X fp32 -> fp8 packed into Xp fragment order ----
        __shared__ unsigned char tile[16 * 512];   // 8 KB, [row][k]
        int rt = bi;
        const float* base = X + (size_t)rt * 16 * 512;
#pragma unroll
        for (int i = 0; i < 8; ++i) {
            float4v v = *reinterpret_cast<const float4v*>(base + (size_t)i * 1024 + t * 4);
            int w = __builtin_amdgcn_cvt_pk_fp8_f32(v[0], v[1], 0, false);
            w = __builtin_amdgcn_cvt_pk_fp8_f32(v[2], v[3], w, true);
            reinterpret_cast<int*>(tile)[i * 256 + t] = w;
        }
        __syncthreads();
        int kp = t >> 5, j = t & 31;
#pragma unroll
        for (int e = 0; e < 2; ++e) {
            int ln = 2 * j + e;
            int l16 = ln & 15, quad = ln >> 4;
            const int* s0 = reinterpret_cast<const int*>(tile + l16 * 512 + (2 * kp) * 32 + quad * 8);
            const int* s1 = reinterpret_cast<const int*>(tile + l16 * 512 + (2 * kp + 1) * 32 + quad * 8);
            int4v o = (int4v){s0[0], s0[1], s1[0], s1[1]};
            *reinterpret_cast<int4v*>(Xp + (((size_t)rt * 8 + kp) * 64 + ln) * 16) = o;
        }
        return;
    }

    if (bi < N_CONVERT_BLOCKS + N_SOFTMAX_BLOCKS) {
        // ---- role B: per-leaf softmax; W' = 512*w packed into Wp ----
        int l = bi - N_CONVERT_BLOCKS;
        int wave = t >> 6, lane = t & 63;
        const float* row = logits + (size_t)l * ATOMS;
        float v0 = row[t];
        float v1 = row[t + 256];
        float v2 = (t == 0) ? row[512] : -1e30f;

        __shared__ float red[8];
        float m = fmaxf(fmaxf(v0, v1), v2);
#pragma unroll
        for (int o = 32; o > 0; o >>= 1) m = fmaxf(m, __shfl_xor(m, o, 64));
        if (lane == 0) red[wave] = m;
        __syncthreads();
        float mx = fmaxf(fmaxf(red[0], red[1]), fmaxf(red[2], red[3]));

        float e0 = __expf(v0 - mx);
        float e1 = __expf(v1 - mx);
        float e2 = (t == 0) ? __expf(v2 - mx) : 0.f;
        float s = e0 + e1 + e2;
#pragma unroll
        for (int o = 32; o > 0; o >>= 1) s += __shfl_xor(s, o, 64);
        if (lane == 0) red[4 + wave] = s;
        __syncthreads();
        float inv = 1.f / (red[4] + red[5] + red[6] + red[7]);
        float inv512 = inv * 512.f;   // keep fp8 near 1.0 (out of subnormal range)

        auto wp_off = [](int l_, int k_) -> size_t {
            int lt = l_ >> 4, l16_ = l_ & 15;
            int ks = k_ >> 5, kp_ = ks >> 1, half = ks & 1;
            int quad_ = (k_ >> 3) & 3, byt = k_ & 7;
            return ((size_t)((lt * 8 + kp_) * 64) + quad_ * 16 + l16_) * 16 + half * 8 + byt;
        };

        if (t == 0) {
            bias[l] = e0 * inv;                      // atom 0 (constant 1), fp32
            Wp[wp_off(l, 511)] = f2fp8(e2 * inv512); // atom 512 -> k=511
        } else {
            Wp[wp_off(l, t - 1)] = f2fp8(e0 * inv512);   // atoms 1..255 -> k=0..254
        }
        Wp[wp_off(l, t + 255)] = f2fp8(e1 * inv512);     // atoms 256..511 -> k=255..510
        return;
    }

    // ---- role C: zero sumexp accumulators + arrival counters (ws poisoned 0xAA) ----
    int i = (bi - N_CONVERT_BLOCKS - N_SOFTMAX_BLOCKS) * 256 + t;
    if (i < BATCH) sumexp[i] = 0.f;
    else { int j = i - BATCH; if (j < 64) cnt[j] = 0; }
}

// ---------------- Kernel 2: fp8 MFMA GEMM + fence-free fused logsumexp finalize ----------------
// Grid: 512 blocks = 64 row-superblocks x 8 leaf-groups (lg fastest).
// Wave: 32 rows x 128 leaves. B panel (64 KB) staged to LDS once, then a
// barrier-free K-loop: per kp, 2 global dwordx4 A-frag loads + 8 ds_read_b128
// B-frag loads + 32 MFMAs (per-dependency waitcnts only).
// Finalize protocol (NO fences — R4 showed agent ACQ_REL fences cost ~19us):
// relaxed device atomicAdds into sumexp; __syncthreads' implicit vmcnt(0)
// drain orders them before the relaxed arrival-counter bump; 8th arrival
// reads totals via atomicAdd(p, 0.0f) RMWs (same coherent point) and writes out.
__global__ __launch_bounds__(256, 2)
void gemm_lse_kernel(const unsigned char* __restrict__ Xp,
                     const unsigned char* __restrict__ Wp,
                     const float* __restrict__ bias,
                     float* __restrict__ sumexp,
                     int* __restrict__ cnt,
                     float* __restrict__ out) {
    __shared__ unsigned char Bl[64 * 1024];   // whole B panel, fragment order
    __shared__ float sums[128];
    __shared__ int lastFlag;

    int tid  = threadIdx.x;
    int wave = tid >> 6;
    int lane = tid & 63;
    int quad = lane >> 4;
    int l16  = lane & 15;

    int lg  = blockIdx.x & 7;    // leaf group: leaves [lg*128, +128)
    int rsb = blockIdx.x >> 3;   // row superblock: rows [rsb*128, +128)

    // one-time B panel stage: wave w covers bytes [w*16K, w*16K+16K)
    {
        const unsigned char* gb = Wp + (size_t)lg * 65536 + wave * 16384 + lane * 16;
        unsigned char* lb = Bl + wave * 16384;   // wave-uniform LDS base
#pragma unroll
        for (int j = 0; j < 16; ++j)
            load_lds16(gb + j * 1024, lb + j * 1024);
    }

    // A fragment pointer (per-lane): rowtiles rt = rsb*8 + wave*2 + mt
    const unsigned char* pa = Xp + ((size_t)(rsb * 8 + wave * 2) * 8) * 1024 + lane * 16;

    // bias prefetch (in flight during the B stage)
    float bl[8];
#pragma unroll
    for (int nt = 0; nt < 8; ++nt)
        bl[nt] = bias[lg * 128 + nt * 16 + l16];

    float4v acc[2][8];
#pragma unroll
    for (int mt = 0; mt < 2; ++mt)
#pragma unroll
        for (int nt = 0; nt < 8; ++nt)
            acc[mt][nt] = (float4v){0.f, 0.f, 0.f, 0.f};

    __syncthreads();   // B panel resident (drains the global_load_lds)

#pragma unroll
    for (int kp = 0; kp < 8; ++kp) {
        long2v af[2], bf[8];
#pragma unroll
        for (int mt = 0; mt < 2; ++mt)
            af[mt] = *reinterpret_cast<const long2v*>(pa + (size_t)mt * 8192 + kp * 1024);
#pragma unroll
        for (int nt = 0; nt < 8; ++nt)
            bf[nt] = *reinterpret_cast<const long2v*>(Bl + (nt * 8 + kp) * 1024 + lane * 16);

#pragma unroll
        for (int mt = 0; mt < 2; ++mt)
#pragma unroll
            for (int nt = 0; nt < 8; ++nt) {
                acc[mt][nt] = __builtin_amdgcn_mfma_f32_16x16x32_fp8_fp8(
                    af[mt][0], bf[nt][0], acc[mt][nt], 0, 0, 0);
                acc[mt][nt] = __builtin_amdgcn_mfma_f32_16x16x32_fp8_fp8(
                    af[mt][1], bf[nt][1], acc[mt][nt], 0, 0, 0);
            }
    }

    // Epilogue: c = acc/512 + bias; sum exp over this wave's 128 leaves
    const float INV512 = 0.001953125f;
    float ps[2][4];
#pragma unroll
    for (int mt = 0; mt < 2; ++mt)
#pragma unroll
        for (int r = 0; r < 4; ++r) ps[mt][r] = 0.f;

#pragma unroll
    for (int nt = 0; nt < 8; ++nt)
#pragma unroll
        for (int mt = 0; mt < 2; ++mt)
#pragma unroll
            for (int r = 0; r < 4; ++r)
                ps[mt][r] += __expf(fmaf(acc[mt][nt][r], INV512, bl[nt]));

    // reduce across the 16 columns (xor masks < 16 stay within the quad group)
#pragma unroll
    for (int m = 1; m < 16; m <<= 1)
#pragma unroll
        for (int mt = 0; mt < 2; ++mt)
#pragma unroll
            for (int r = 0; r < 4; ++r)
                ps[mt][r] += __shfl_xor(ps[mt][r], m, 64);

    if (l16 == 0) {
#pragma unroll
        for (int mt = 0; mt < 2; ++mt)
#pragma unroll
            for (int r = 0; r < 4; ++r)
                sums[wave * 32 + mt * 16 + quad * 4 + r] = ps[mt][r];
    }
    __syncthreads();

    // relaxed device-scope accumulation (no fences)
    if (tid < 128)
        __hip_atomic_fetch_add(&sumexp[rsb * 128 + tid], sums[tid],
                               __ATOMIC_RELAXED, __HIP_MEMORY_SCOPE_AGENT);
    __syncthreads();   // implicit vmcnt(0): this block's adds are ack'd

    if (tid == 0) {
        int old = __hip_atomic_fetch_add(&cnt[rsb], 1,
                                         __ATOMIC_RELAXED, __HIP_MEMORY_SCOPE_AGENT);
        lastFlag = (old == 7);
    }
    __syncthreads();

    if (lastFlag && tid < 128) {
        // RMW read at the same coherent point the adds landed at
        float s = __hip_atomic_fetch_add(&sumexp[rsb * 128 + tid], 0.0f,
                                         __ATOMIC_RELAXED, __HIP_MEMORY_SCOPE_AGENT);
        out[rsb * 128 + tid] = logf(s);
    }
}

extern "C" void kernel_launch(void* const* d_in, const int* in_sizes, int n_in,
                              void* d_out, int out_size, void* d_ws, size_t ws_size,
                              hipStream_t stream) {
    const float* X      = (const float*)d_in[0];   // (8192, 512) fp32
    const float* logits = (const float*)d_in[1];   // (1024, 513) fp32
    float* out = (float*)d_out;                    // (8192,) fp32

    char* ws = (char*)d_ws;
    unsigned char* Xp = (unsigned char*)ws;                                  // 4 MB
    unsigned char* Wp = (unsigned char*)(ws + (size_t)BATCH * NF);           // 512 KB
    float* bias   = (float*)(ws + (size_t)BATCH * NF + (size_t)NL * NF);     // 4 KB
    float* sumexp = (float*)((char*)bias + NL * sizeof(float));              // 32 KB
    int*   cnt    = (int*)((char*)sumexp + BATCH * sizeof(float));           // 256 B

    prep_kernel<<<N_CONVERT_BLOCKS + N_SOFTMAX_BLOCKS + N_ZERO_BLOCKS, 256, 0, stream>>>(
        X, logits, Xp, Wp, bias, sumexp, cnt);
    gemm_lse_kernel<<<(BATCH / 128) * (NL / 128), 256, 0, stream>>>(
        Xp, Wp, bias, sumexp, cnt, out);
}